// Round 9
// baseline (105.193 us; speedup 1.0000x reference)
//
#include <hip/hip_runtime.h>
#include <hip/hip_bf16.h>

typedef unsigned short u16;
typedef unsigned int u32;
typedef __bf16 bf16x8_t __attribute__((ext_vector_type(8)));
typedef float f32x4_t __attribute__((ext_vector_type(4)));
typedef float f32x16 __attribute__((ext_vector_type(16)));

constexpr int Bb = 4;
constexpr int Tt = 4096;
constexpr int Dd = 64;
constexpr float QSCALE = 0.18033688011112042f; // 0.125 * log2(e), folded into q

// MEASUREMENT ROUND (R9): flash repeats its accumulation NREP times (identical math, output
// unchanged -- last rep is the canonical one). dur_us = base + (NREP-1)*T_flash gives T_flash
// directly, and the 3x-long flash dispatch finally exceeds the 42us harness fills so rocprof
// top-5 shows OUR counters (MfmaUtil/VALUBusy/FETCH/conflicts) for the first time.
constexpr int NREP = 3;

__device__ __forceinline__ u16 f2bf(float f) { // RNE
  unsigned int u = __builtin_bit_cast(unsigned int, f);
  return (u16)((u + 0x7fffu + ((u >> 16) & 1u)) >> 16);
}
__device__ __forceinline__ u32 pk2(float a, float b) { // RNE pack
  return (u32)f2bf(a) | ((u32)f2bf(b) << 16);
}
__device__ __forceinline__ u32 pkt(float a, float b) { // truncation pack (3 inst)
  const u32 ua = __builtin_bit_cast(u32, a);
  const u32 ub = __builtin_bit_cast(u32, b);
  return (ua >> 16) | (ub & 0xFFFF0000u);
}
__device__ __forceinline__ bf16x8_t ld16(const u16* p) {
  int4 v = *(const int4*)p;
  return __builtin_bit_cast(bf16x8_t, v);
}
__device__ __forceinline__ f32x4_t mfma16(bf16x8_t a, bf16x8_t b, f32x4_t c) {
  return __builtin_amdgcn_mfma_f32_16x16x32_bf16(a, b, c, 0, 0, 0);
}
__device__ __forceinline__ f32x16 mfma32(bf16x8_t a, bf16x8_t b, f32x16 c) {
  return __builtin_amdgcn_mfma_f32_32x32x16_bf16(a, b, c, 0, 0, 0);
}

// ---------------- proj v4 (R17, verified): LDS-staged x and W, fragment-order outputs ----------------
__global__ __launch_bounds__(256) void HeadV1_proj(
    const float* __restrict__ x, const float* __restrict__ Wk,
    const float* __restrict__ Wq, const float* __restrict__ Wv,
    u16* __restrict__ qS, u16* __restrict__ kS, u16* __restrict__ vS)
{
  __shared__ u16 xl[64][72];      // 9216 B
  __shared__ u16 Wl[3][64][72];   // 27648 B
  __shared__ u16 ylds[64][72];    // 9216 B  (total 46 KB)

  const int t = threadIdx.x;
  const int w = t >> 6, lane = t & 63, l15 = lane & 15, quad = lane >> 4;
  const int r0 = blockIdx.x * 64;
  const int b  = r0 >> 12;
  const int kt = (r0 & 4095) >> 6;
  const long tilebase = ((long)(b * 64 + kt)) * 4096;

  { // coalesced fp32 staging with one-time bf16 conversion
    const float* srcs[4] = {x + (long)r0 * 64, Wk, Wq, Wv};
    u16* dstl[4] = {&xl[0][0], &Wl[0][0][0], &Wl[1][0][0], &Wl[2][0][0]};
    #pragma unroll
    for (int mm = 0; mm < 4; mm++) {
      const float* s = srcs[mm];
      u16* d = dstl[mm];
      #pragma unroll
      for (int i = 0; i < 4; i++) {
        const int f4 = i * 256 + t;        // 1024 float4 per 64x64 tile
        const int row = f4 >> 4, c4 = f4 & 15;
        float4 v = ((const float4*)(s + row * 64))[c4];
        uint2 pk;
        pk.x = pk2(v.x, v.y);
        pk.y = pk2(v.z, v.w);
        *(uint2*)(d + row * 72 + c4 * 4) = pk;
      }
    }
  }
  __syncthreads();

  bf16x8_t xf[2];
  #pragma unroll
  for (int kh = 0; kh < 2; kh++)
    xf[kh] = ld16(&xl[w * 16 + l15][kh * 32 + quad * 8]);

  u16* dsts[3];
  dsts[0] = kS + tilebase; dsts[1] = qS + tilebase; dsts[2] = vS + tilebase;

  #pragma unroll
  for (int m = 0; m < 3; m++) {
    float vals[4][4];
    #pragma unroll
    for (int g = 0; g < 4; g++) {
      f32x4_t acc = {0.f, 0.f, 0.f, 0.f};
      #pragma unroll
      for (int kh = 0; kh < 2; kh++) {
        bf16x8_t wf = ld16(&Wl[m][g * 16 + l15][kh * 32 + quad * 8]);
        acc = mfma16(xf[kh], wf, acc);
      }
      #pragma unroll
      for (int r = 0; r < 4; r++)
        vals[g][r] = (m == 1) ? acc[r] * QSCALE : acc[r];
    }
    #pragma unroll
    for (int g = 0; g < 4; g++)
      #pragma unroll
      for (int r = 0; r < 4; r++)
        ylds[w * 16 + quad * 4 + r][g * 16 + l15] = f2bf(vals[g][r]);
    __syncthreads();
    if (m < 2) {
      #pragma unroll
      for (int kk = 0; kk < 2; kk++) {
        bf16x8_t f = ld16(&ylds[w * 16 + l15][kk * 32 + quad * 8]);
        *(int4*)(dsts[m] + (w * 2 + kk) * 512 + lane * 8) = __builtin_bit_cast(int4, f);
      }
    } else {
      #pragma unroll
      for (int kk = 0; kk < 2; kk++) {
        u16 tmp[8];
        #pragma unroll
        for (int j = 0; j < 8; j++)
          tmp[j] = ylds[kk * 32 + quad * 8 + j][w * 16 + l15];
        *(int4*)(dsts[2] + (kk * 4 + w) * 512 + lane * 8) = *(const int4*)tmp;
      }
    }
    __syncthreads();
  }
}

// ---------------- flash v15 x NREP (R8 kernel, accumulation repeated for timing) ----------------
__global__ __launch_bounds__(1024, 4) void HeadV1_flash(
    const u16* __restrict__ qS, const u16* __restrict__ kS,
    const u16* __restrict__ vS, float* __restrict__ outg)
{
  __shared__ __align__(16) char smem[55296];
  float (*chk)[16][33]  = (float (*)[16][33])smem;              // [16][16][33] f32 = 33792 B
  float (*stg)[32][68]  = (float (*)[32][68])(smem + 33792);    // [2][32][68]  f32 = 17408 B
  float (*lst)[2][32]   = (float (*)[2][32])(smem + 51200);     // [16][2][32]  f32 =  4096 B

  const int t    = threadIdx.x;
  const int w    = t >> 6;        // 0..15
  const int lane = t & 63;
  const int l15  = lane & 15;
  const int lhb  = lane >> 5;     // half-of-wave
  const int l4   = (lane >> 4) & 1;
  const int q31  = lane & 31;

  const int xcd = blockIdx.x & 7;
  const int b   = xcd >> 1;                              // batch locked to XCD pair (R7)
  const int i   = ((blockIdx.x >> 3) << 1) | (xcd & 1);  // 0..63
  const int j1 = i, j2 = 127 - i;
  const int nk1 = (j1 >> 1) + 1;
  const int nk2 = (j2 >> 1) + 1;       // nk1 + nk2 == 65
  int n1 = (16 * nk1 + 32) / 65;       // round(16*nk1/65)
  if (n1 < 1) n1 = 1;
  if (n1 > 15) n1 = 15;

  const bool grp2 = (w >= n1);
  const int j   = grp2 ? j2 : j1;
  const int nk  = grp2 ? nk2 : nk1;
  const int str = grp2 ? (16 - n1) : n1;
  const int off = grp2 ? (w - n1) : w;

  const int qt64 = j >> 1;
  const int ql0  = (j & 1) * 32;
  const int qr0  = j * 32;
  const long base = (long)b * Tt * Dd;

  // Q fragments: B-operand of 32x32x16, B[k=d][col=q]: lane -> Q[ql0+q31][dsl*16 + lhb*8 + j]
  const u16* qt_ = qS + ((long)(b * 64 + qt64)) * 4096;
  bf16x8_t qfrag[4];
  #pragma unroll
  for (int dsl = 0; dsl < 4; dsl++)
    qfrag[dsl] = ld16(qt_ + (((ql0 >> 4) + l4) * 2 + (dsl >> 1)) * 512
                          + (((dsl * 2 + lhb) & 3) * 16 + l15) * 8);

  f32x16 O0, O1;
  float Lp;

  const u16* kb = kS + ((long)(b * 64)) * 4096;
  const u16* vb = vS + ((long)(b * 64)) * 4096;

  #pragma unroll 1
  for (int rep = 0; rep < NREP; rep++) {
    O0 = f32x16{0.f,0.f,0.f,0.f,0.f,0.f,0.f,0.f,0.f,0.f,0.f,0.f,0.f,0.f,0.f,0.f};
    O1 = O0;
    Lp = 0.f;

    for (int kt = off; kt < nk; kt += str) {
      const bool ismask = (kt == nk - 1);
      const u16* ktile = kb + (long)kt * 4096;
      const u16* vtile = vb + (long)kt * 4096;
      // even-j diagonal tiles: upper kv-32 fully masked -> skip entirely
      const int nh = (ismask && !(j & 1)) ? 1 : 2;

      for (int h2 = 0; h2 < nh; h2++) {
        // K fragments: A[row=kv=h2*32+(lane&31)][k=d slice]
        bf16x8_t kf[4];
        #pragma unroll
        for (int dsl = 0; dsl < 4; dsl++)
          kf[dsl] = ld16(ktile + ((h2 * 2 + l4) * 2 + (dsl >> 1)) * 512
                               + (((dsl * 2 + lhb) & 3) * 16 + l15) * 8);
        // V fragments: A[row=d=dh*32+(lane&31)][k=kv slice ksl*16+lhb*8]
        bf16x8_t vf[2][2];
        #pragma unroll
        for (int ksl = 0; ksl < 2; ksl++)
          #pragma unroll
          for (int dh = 0; dh < 2; dh++)
            vf[ksl][dh] = ld16(vtile + (h2 * 4 + dh * 2 + l4) * 512
                                     + ((ksl * 2 + lhb) * 16 + l15) * 8);

        f32x16 S = {0.f,0.f,0.f,0.f,0.f,0.f,0.f,0.f,0.f,0.f,0.f,0.f,0.f,0.f,0.f,0.f};
        #pragma unroll
        for (int dsl = 0; dsl < 4; dsl++)
          S = mfma32(kf[dsl], qfrag[dsl], S);

        if (ismask && h2 == (j & 1)) {   // diagonal kv-32 only
          const int kvb = kt * 64 + h2 * 32 + 4 * lhb;
          const int qi  = qr0 + q31;
          #pragma unroll
          for (int r = 0; r < 16; r++) {
            const int kvg = kvb + (r & 3) + 8 * (r >> 2);
            if (kvg > qi) S[r] = -1e30f;   // exp2 -> 0
          }
        }

        float p[16];
        #pragma unroll
        for (int r = 0; r < 16; r++) p[r] = __builtin_amdgcn_exp2f(S[r]);
        #pragma unroll
        for (int r = 0; r < 16; r++) {   // L sums EXACTLY the truncated values PV consumes
          const u32 u = __builtin_bit_cast(u32, p[r]) & 0xFFFF0000u;
          Lp += __builtin_bit_cast(float, u);
        }

        #pragma unroll
        for (int ksl = 0; ksl < 2; ksl++) {
          const u32 a0 = pkt(p[8 * ksl + 0], p[8 * ksl + 1]);
          const u32 a1 = pkt(p[8 * ksl + 2], p[8 * ksl + 3]);
          const u32 a2 = pkt(p[8 * ksl + 4], p[8 * ksl + 5]);
          const u32 a3 = pkt(p[8 * ksl + 6], p[8 * ksl + 7]);
          // partner exchange: lo needs hi's a0,a1 (words 2,3); hi needs lo's a2,a3 (words 0,1)
          const u32 x02 = (u32)__shfl_xor((int)(lhb ? a0 : a2), 32);
          const u32 x13 = (u32)__shfl_xor((int)(lhb ? a1 : a3), 32);
          uint4 bw;
          bw.x = lhb ? x02 : a0;
          bw.y = lhb ? x13 : a1;
          bw.z = lhb ? a2 : x02;
          bw.w = lhb ? a3 : x13;
          const bf16x8_t Bf = __builtin_bit_cast(bf16x8_t, bw);
          __builtin_amdgcn_s_setprio(1);
          O0 = mfma32(vf[ksl][0], Bf, O0);
          O1 = mfma32(vf[ksl][1], Bf, O1);
          __builtin_amdgcn_s_setprio(0);
        }
      }
    }
    // keep reps 0..NREP-2 alive (rule #17: ablation-via-skip DCEs upstream ops)
    asm volatile("" :: "v"(O0[0] + O1[0] + Lp));
  }

  // ---- 16-wave merge, per-j wave ranges [0,n1) / [n1,16) ----
  lst[w][lhb][q31] = Lp;   // 64 lanes -> 64 distinct slots
  __syncthreads();

  #pragma unroll
  for (int rr = 0; rr < 4; rr++) {   // d_global = rr*16 + dloc
    #pragma unroll
    for (int rs = 0; rs < 8; rs++) {
      const int dloc = (rs & 3) + 8 * (rs >> 2) + 4 * lhb;
      const float val = (rr >> 1) ? ((rr & 1) ? O1[8 + rs] : O1[rs])
                                  : ((rr & 1) ? O0[8 + rs] : O0[rs]);
      chk[w][dloc][q31] = val;
    }
    __syncthreads();
    {
      const int jsel = t >> 9, tt = t & 511;
      const int d2 = tt >> 5, q = tt & 31;   // 512 threads = 16 d x 32 q per jsel
      const int lo = jsel ? n1 : 0, hi = jsel ? 16 : n1;
      float s = 0.f;
      for (int w2 = lo; w2 < hi; w2++) s += chk[w2][d2][q];
      stg[jsel][q][rr * 16 + d2] = s;
    }
    __syncthreads();
  }

  { // normalize + coalesced fp32 write: per jsel, 32 q x 64 d (512 thr x 16 B)
    const int jsel = t >> 9, tt = t & 511;
    const int q = tt >> 4, dg = tt & 15;
    const int lo = jsel ? n1 : 0, hi = jsel ? 16 : n1;
    float L = 0.f;
    for (int w2 = lo; w2 < hi; w2++) L += lst[w2][0][q] + lst[w2][1][q];
    const float invL = 1.0f / L;
    const int jj = jsel ? j2 : j1;
    float4 v = *(const float4*)&stg[jsel][q][dg * 4];
    v.x *= invL; v.y *= invL; v.z *= invL; v.w *= invL;
    *(float4*)(outg + base + (long)(jj * 32 + q) * 64 + dg * 4) = v;
  }
}

extern "C" void kernel_launch(void* const* d_in, const int* in_sizes, int n_in,
                              void* d_out, int out_size, void* d_ws, size_t ws_size,
                              hipStream_t stream) {
  (void)in_sizes; (void)n_in; (void)out_size; (void)ws_size;
  const float* x  = (const float*)d_in[0];
  const float* Wk = (const float*)d_in[1];
  const float* Wq = (const float*)d_in[2];
  const float* Wv = (const float*)d_in[3];
  float* out = (float*)d_out;
  // workspace: qS 2MB | kS 2MB | vS 2MB (all in MFMA-fragment order)
  u16* qw  = (u16*)d_ws;
  u16* kw  = qw + (size_t)Bb * Tt * Dd;
  u16* vw  = kw + (size_t)Bb * Tt * Dd;

  HeadV1_proj<<<(Bb * Tt) / 64, 256, 0, stream>>>(x, Wk, Wq, Wv, qw, kw, vw);
  HeadV1_flash<<<256, 1024, 0, stream>>>(qw, kw, vw, out);
}

// Round 10
// 82.919 us; speedup vs baseline: 1.2686x; 1.2686x over previous
//
#include <hip/hip_runtime.h>
#include <hip/hip_bf16.h>

typedef unsigned short u16;
typedef unsigned int u32;
typedef __bf16 bf16x8_t __attribute__((ext_vector_type(8)));
typedef float f32x4_t __attribute__((ext_vector_type(4)));
typedef float f32x16 __attribute__((ext_vector_type(16)));

constexpr int Bb = 4;
constexpr int Tt = 4096;
constexpr int Dd = 64;
constexpr float QSCALE = 0.18033688011112042f; // 0.125 * log2(e), folded into q

__device__ __forceinline__ u16 f2bf(float f) { // RNE
  unsigned int u = __builtin_bit_cast(unsigned int, f);
  return (u16)((u + 0x7fffu + ((u >> 16) & 1u)) >> 16);
}
__device__ __forceinline__ u32 pk2(float a, float b) { // RNE pack
  return (u32)f2bf(a) | ((u32)f2bf(b) << 16);
}
__device__ __forceinline__ u32 pkt(float a, float b) { // truncation pack (3 inst)
  const u32 ua = __builtin_bit_cast(u32, a);
  const u32 ub = __builtin_bit_cast(u32, b);
  return (ua >> 16) | (ub & 0xFFFF0000u);
}
__device__ __forceinline__ bf16x8_t ld16(const u16* p) {
  int4 v = *(const int4*)p;
  return __builtin_bit_cast(bf16x8_t, v);
}
__device__ __forceinline__ f32x4_t mfma16(bf16x8_t a, bf16x8_t b, f32x4_t c) {
  return __builtin_amdgcn_mfma_f32_16x16x32_bf16(a, b, c, 0, 0, 0);
}
__device__ __forceinline__ f32x16 mfma32(bf16x8_t a, bf16x8_t b, f32x16 c) {
  return __builtin_amdgcn_mfma_f32_32x32x16_bf16(a, b, c, 0, 0, 0);
}

// ---------------- proj v5: R6's 16-wave restructure, standalone (R6-verified logic) ----------------
// 1024 thr: staging = 1 float4/thread per source (4 total); wave-groups mg=0/1/2 compute k/q/v
// GEMMs in PARALLEL (waves 12-15 idle in compute); 2 barriers instead of 6. 16 waves/CU vs 4.
__global__ __launch_bounds__(1024) void HeadV1_proj(
    const float* __restrict__ x, const float* __restrict__ Wk,
    const float* __restrict__ Wq, const float* __restrict__ Wv,
    u16* __restrict__ qS, u16* __restrict__ kS, u16* __restrict__ vS)
{
  __shared__ u16 xl[64][72];       //  9216 B
  __shared__ u16 Wl[3][64][72];    // 27648 B
  __shared__ u16 yl[3][64][72];    // 27648 B (total 64512 B)

  const int t = threadIdx.x;
  const int w = t >> 6, lane = t & 63, l15 = lane & 15, quad = lane >> 4;
  const int blk = blockIdx.x;
  const int r0 = blk * 64;
  const int b  = blk >> 6;
  const int kt = blk & 63;
  const long tilebase = ((long)(b * 64 + kt)) * 4096;

  { // staging: 1024 threads x 1 float4 per source tile
    const float* srcs[4] = {x + (long)r0 * 64, Wk, Wq, Wv};
    u16* dstl[4] = {&xl[0][0], &Wl[0][0][0], &Wl[1][0][0], &Wl[2][0][0]};
    const int row = t >> 4, c4 = t & 15;
    #pragma unroll
    for (int mm = 0; mm < 4; mm++) {
      float4 v = ((const float4*)(srcs[mm] + row * 64))[c4];
      uint2 pk;
      pk.x = pk2(v.x, v.y);
      pk.y = pk2(v.z, v.w);
      *(uint2*)(dstl[mm] + row * 72 + c4 * 4) = pk;
    }
  }
  __syncthreads();

  const int mg = w >> 2;       // wave group: 0=k 1=q 2=v 3=idle
  const int wl = w & 3;        // wave-in-group
  if (mg < 3) {
    bf16x8_t xf[2];
    #pragma unroll
    for (int kh = 0; kh < 2; kh++)
      xf[kh] = ld16(&xl[wl * 16 + l15][kh * 32 + quad * 8]);

    float vals[4][4];
    #pragma unroll
    for (int g = 0; g < 4; g++) {
      f32x4_t acc = {0.f, 0.f, 0.f, 0.f};
      #pragma unroll
      for (int kh = 0; kh < 2; kh++) {
        bf16x8_t wf = ld16(&Wl[mg][g * 16 + l15][kh * 32 + quad * 8]);
        acc = mfma16(xf[kh], wf, acc);
      }
      #pragma unroll
      for (int r = 0; r < 4; r++)
        vals[g][r] = (mg == 1) ? acc[r] * QSCALE : acc[r];
    }
    #pragma unroll
    for (int g = 0; g < 4; g++)
      #pragma unroll
      for (int r = 0; r < 4; r++)
        yl[mg][wl * 16 + quad * 4 + r][g * 16 + l15] = f2bf(vals[g][r]);
  }
  __syncthreads();

  if (mg < 3) {
    u16* dsts[3];
    dsts[0] = kS + tilebase; dsts[1] = qS + tilebase; dsts[2] = vS + tilebase;
    if (mg < 2) {
      #pragma unroll
      for (int kk = 0; kk < 2; kk++) {
        bf16x8_t f = ld16(&yl[mg][wl * 16 + l15][kk * 32 + quad * 8]);
        *(int4*)(dsts[mg] + (wl * 2 + kk) * 512 + lane * 8) = __builtin_bit_cast(int4, f);
      }
    } else {
      #pragma unroll
      for (int kk = 0; kk < 2; kk++) {
        u16 tmp[8];
        #pragma unroll
        for (int jj = 0; jj < 8; jj++)
          tmp[jj] = yl[2][kk * 32 + quad * 8 + jj][wl * 16 + l15];
        *(int4*)(dsts[2] + (kk * 4 + wl) * 512 + lane * 8) = *(const int4*)tmp;
      }
    }
  }
}

// ---------------- flash v16: v15 + L via ones-MFMA (VALU -25%), exp fused into pack ----------------
// L[q] = sum_kv bf16(P[kv][q]) computed as Lacc = mfma32(ones, Bf, Lacc) -- sums EXACTLY the
// addends PV consumes (A=ones is layout-independent; every C reg holds the column sum).
// Replaces 32 VALU ops/half with 1 MFMA (matrix pipe at 23%, has headroom). p[16] array gone.
__global__ __launch_bounds__(1024, 4) void HeadV1_flash(
    const u16* __restrict__ qS, const u16* __restrict__ kS,
    const u16* __restrict__ vS, float* __restrict__ outg)
{
  __shared__ __align__(16) char smem[55296];
  float (*chk)[16][33]  = (float (*)[16][33])smem;              // [16][16][33] f32 = 33792 B
  float (*stg)[32][68]  = (float (*)[32][68])(smem + 33792);    // [2][32][68]  f32 = 17408 B
  float (*lst)[2][32]   = (float (*)[2][32])(smem + 51200);     // [16][2][32]  f32 =  4096 B

  const int t    = threadIdx.x;
  const int w    = t >> 6;        // 0..15
  const int lane = t & 63;
  const int l15  = lane & 15;
  const int lhb  = lane >> 5;     // half-of-wave
  const int l4   = (lane >> 4) & 1;
  const int q31  = lane & 31;

  const int xcd = blockIdx.x & 7;
  const int b   = xcd >> 1;                              // batch locked to XCD pair (R7)
  const int i   = ((blockIdx.x >> 3) << 1) | (xcd & 1);  // 0..63
  const int j1 = i, j2 = 127 - i;
  const int nk1 = (j1 >> 1) + 1;
  const int nk2 = (j2 >> 1) + 1;       // nk1 + nk2 == 65
  int n1 = (16 * nk1 + 32) / 65;       // round(16*nk1/65)
  if (n1 < 1) n1 = 1;
  if (n1 > 15) n1 = 15;

  const bool grp2 = (w >= n1);
  const int j   = grp2 ? j2 : j1;
  const int nk  = grp2 ? nk2 : nk1;
  const int str = grp2 ? (16 - n1) : n1;
  const int off = grp2 ? (w - n1) : w;

  const int qt64 = j >> 1;
  const int ql0  = (j & 1) * 32;
  const int qr0  = j * 32;
  const long base = (long)b * Tt * Dd;

  union { u32 u4[4]; bf16x8_t v; } uo;
  uo.u4[0] = uo.u4[1] = uo.u4[2] = uo.u4[3] = 0x3F803F80u; // bf16 1.0 x8
  const bf16x8_t ones = uo.v;

  // Q fragments: B-operand of 32x32x16, B[k=d][col=q]: lane -> Q[ql0+q31][dsl*16 + lhb*8 + j]
  const u16* qt_ = qS + ((long)(b * 64 + qt64)) * 4096;
  bf16x8_t qfrag[4];
  #pragma unroll
  for (int dsl = 0; dsl < 4; dsl++)
    qfrag[dsl] = ld16(qt_ + (((ql0 >> 4) + l4) * 2 + (dsl >> 1)) * 512
                          + (((dsl * 2 + lhb) & 3) * 16 + l15) * 8);

  f32x16 O0 = {0.f,0.f,0.f,0.f,0.f,0.f,0.f,0.f,0.f,0.f,0.f,0.f,0.f,0.f,0.f,0.f};
  f32x16 O1 = O0;
  f32x16 Lacc = O0;

  const u16* kb = kS + ((long)(b * 64)) * 4096;
  const u16* vb = vS + ((long)(b * 64)) * 4096;

  for (int kt = off; kt < nk; kt += str) {
    const bool ismask = (kt == nk - 1);
    const u16* ktile = kb + (long)kt * 4096;
    const u16* vtile = vb + (long)kt * 4096;
    // even-j diagonal tiles: upper kv-32 fully masked -> skip entirely
    const int nh = (ismask && !(j & 1)) ? 1 : 2;

    for (int h2 = 0; h2 < nh; h2++) {
      // K fragments: A[row=kv=h2*32+(lane&31)][k=d slice]
      bf16x8_t kf[4];
      #pragma unroll
      for (int dsl = 0; dsl < 4; dsl++)
        kf[dsl] = ld16(ktile + ((h2 * 2 + l4) * 2 + (dsl >> 1)) * 512
                             + (((dsl * 2 + lhb) & 3) * 16 + l15) * 8);
      // V fragments: A[row=d=dh*32+(lane&31)][k=kv slice ksl*16+lhb*8]
      bf16x8_t vf[2][2];
      #pragma unroll
      for (int ksl = 0; ksl < 2; ksl++)
        #pragma unroll
        for (int dh = 0; dh < 2; dh++)
          vf[ksl][dh] = ld16(vtile + (h2 * 4 + dh * 2 + l4) * 512
                                   + ((ksl * 2 + lhb) * 16 + l15) * 8);

      f32x16 S = {0.f,0.f,0.f,0.f,0.f,0.f,0.f,0.f,0.f,0.f,0.f,0.f,0.f,0.f,0.f,0.f};
      #pragma unroll
      for (int dsl = 0; dsl < 4; dsl++)
        S = mfma32(kf[dsl], qfrag[dsl], S);

      if (ismask && h2 == (j & 1)) {   // diagonal kv-32 only
        const int kvb = kt * 64 + h2 * 32 + 4 * lhb;
        const int qi  = qr0 + q31;
        #pragma unroll
        for (int r = 0; r < 16; r++) {
          const int kvg = kvb + (r & 3) + 8 * (r >> 2);
          if (kvg > qi) S[r] = -1e30f;   // exp2 -> 0
        }
      }

      #pragma unroll
      for (int ksl = 0; ksl < 2; ksl++) {
        const u32 a0 = pkt(__builtin_amdgcn_exp2f(S[8 * ksl + 0]),
                           __builtin_amdgcn_exp2f(S[8 * ksl + 1]));
        const u32 a1 = pkt(__builtin_amdgcn_exp2f(S[8 * ksl + 2]),
                           __builtin_amdgcn_exp2f(S[8 * ksl + 3]));
        const u32 a2 = pkt(__builtin_amdgcn_exp2f(S[8 * ksl + 4]),
                           __builtin_amdgcn_exp2f(S[8 * ksl + 5]));
        const u32 a3 = pkt(__builtin_amdgcn_exp2f(S[8 * ksl + 6]),
                           __builtin_amdgcn_exp2f(S[8 * ksl + 7]));
        // partner exchange: lo needs hi's a0,a1 (words 2,3); hi needs lo's a2,a3 (words 0,1)
        const u32 x02 = (u32)__shfl_xor((int)(lhb ? a0 : a2), 32);
        const u32 x13 = (u32)__shfl_xor((int)(lhb ? a1 : a3), 32);
        uint4 bw;
        bw.x = lhb ? x02 : a0;
        bw.y = lhb ? x13 : a1;
        bw.z = lhb ? a2 : x02;
        bw.w = lhb ? a3 : x13;
        const bf16x8_t Bf = __builtin_bit_cast(bf16x8_t, bw);
        Lacc = mfma32(ones, Bf, Lacc);   // L off the VALU: sums the exact PV addends
        __builtin_amdgcn_s_setprio(1);
        O0 = mfma32(vf[ksl][0], Bf, O0);
        O1 = mfma32(vf[ksl][1], Bf, O1);
        __builtin_amdgcn_s_setprio(0);
      }
    }
  }

  // ---- 16-wave merge, per-j wave ranges [0,n1) / [n1,16) ----
  lst[w][lhb][q31] = Lacc[0];   // every C reg holds the column sum; both lhb copies identical
  __syncthreads();

  #pragma unroll
  for (int rr = 0; rr < 4; rr++) {   // d_global = rr*16 + dloc
    #pragma unroll
    for (int rs = 0; rs < 8; rs++) {
      const int dloc = (rs & 3) + 8 * (rs >> 2) + 4 * lhb;
      const float val = (rr >> 1) ? ((rr & 1) ? O1[8 + rs] : O1[rs])
                                  : ((rr & 1) ? O0[8 + rs] : O0[rs]);
      chk[w][dloc][q31] = val;
    }
    __syncthreads();
    {
      const int jsel = t >> 9, tt = t & 511;
      const int d2 = tt >> 5, q = tt & 31;   // 512 threads = 16 d x 32 q per jsel
      const int lo = jsel ? n1 : 0, hi = jsel ? 16 : n1;
      float s = 0.f;
      for (int w2 = lo; w2 < hi; w2++) s += chk[w2][d2][q];
      stg[jsel][q][rr * 16 + d2] = s;
    }
    __syncthreads();
  }

  { // normalize + coalesced fp32 write: per jsel, 32 q x 64 d (512 thr x 16 B)
    const int jsel = t >> 9, tt = t & 511;
    const int q = tt >> 4, dg = tt & 15;
    const int lo = jsel ? n1 : 0, hi = jsel ? 16 : n1;
    float L = 0.f;
    for (int w2 = lo; w2 < hi; w2++) L += lst[w2][0][q];   // [0] only: lhb copies equal
    const float invL = 1.0f / L;
    const int jj = jsel ? j2 : j1;
    float4 v = *(const float4*)&stg[jsel][q][dg * 4];
    v.x *= invL; v.y *= invL; v.z *= invL; v.w *= invL;
    *(float4*)(outg + base + (long)(jj * 32 + q) * 64 + dg * 4) = v;
  }
}

extern "C" void kernel_launch(void* const* d_in, const int* in_sizes, int n_in,
                              void* d_out, int out_size, void* d_ws, size_t ws_size,
                              hipStream_t stream) {
  (void)in_sizes; (void)n_in; (void)out_size; (void)ws_size;
  const float* x  = (const float*)d_in[0];
  const float* Wk = (const float*)d_in[1];
  const float* Wq = (const float*)d_in[2];
  const float* Wv = (const float*)d_in[3];
  float* out = (float*)d_out;
  // workspace: qS 2MB | kS 2MB | vS 2MB (all in MFMA-fragment order)
  u16* qw  = (u16*)d_ws;
  u16* kw  = qw + (size_t)Bb * Tt * Dd;
  u16* vw  = kw + (size_t)Bb * Tt * Dd;

  HeadV1_proj<<<(Bb * Tt) / 64, 1024, 0, stream>>>(x, Wk, Wq, Wv, qw, kw, vw);
  HeadV1_flash<<<256, 1024, 0, stream>>>(qw, kw, vw, out);
}